// Round 4
// baseline (121.805 us; speedup 1.0000x reference)
//
#include <hip/hip_runtime.h>
#include <hip/hip_fp16.h>

// Problem constants (fixed by the reference)
constexpr int L = 64;     // sites
constexpr int P = 4;      // physical dim
constexpr int D = 128;    // bond dim
constexpr int B = 2048;   // batch
constexpr int EPW = 16;   // batch elements per WG (one mfma M-tile)
constexpr int NG = B / EPW;   // 128 batch groups -> 256 WGs (fwd+bwd)

using v8h = __attribute__((ext_vector_type(8))) _Float16;  // mfma A/B frag
using v4f = __attribute__((ext_vector_type(4))) float;     // mfma C/D frag

// ---- workspace layout (bytes); TOTAL 10 MB ------------------------------
constexpr size_t UT_OFF  = 0;               // u_t fp32 [d][b]   1 MB
constexpr size_t WT_OFF  = 1048576;         // w_t fp32 [d][b]   1 MB
constexpr size_t MTF_OFF = 2097152;         // sites 0..31  fp16 frag-layout 4 MB
constexpr size_t MTB_OFF = 6291456;         // sites 32..63 fp16 frag-layout 4 MB
// frag layout (fp16 units): [site][p][kh][w][q4][me][j]
//   site stride 65536, p 16384, kh 4096, w 512, q4 128, me 8, j 1
// frag (p,kh) for lane (w,q4,me) = B^T[col=w*16+me][k=(kh*4+q4)*8 + j]
// -> one global_load_dwordx4 per frag, 64 lanes = 1 KB contiguous.

// s_waitcnt immediates (gfx9: vmcnt[3:0] | exp<<4 | lgkm<<8 | vmcnt[5:4]<<14)
#define WAIT_LGKM0 0xC07F  // lgkmcnt(0) only; vmcnt untouched

// ---------------------------------------------------------------------------
// Convert fp32 src[site][p][d][c] (row-major 128x128) into frag layout.
//   fwd (sites 0..31):  B^T[col][k] = M[k][col]  -> column gather (register
//     transpose, 64B-coalesced across me-lanes)
//   bwd (sites 32..63): B^T[col][k] = M[col][k]  -> row slice, fully
//     coalesced float4 reads AND v8h writes.
// R11: grid 1024 = (mat, kh-quarter) — 2x blocks vs R10 for the
// latency-bound gather (was 4 waves/CU effective occupancy).
// ---------------------------------------------------------------------------
__global__ void convert_dual(const float* __restrict__ src,
                             _Float16* __restrict__ mtf,
                             _Float16* __restrict__ mtb) {
  const int mat = blockIdx.x >> 2;    // site*P + p
  const int kh  = blockIdx.x & 3;     // my k-half quarter
  const int site = mat >> 2, p = mat & 3;
  const int wave = threadIdx.x >> 6, lane = threadIdx.x & 63;
  const int me = lane & 15, q4 = lane >> 4;
  const float* sb = src + (size_t)mat * 16384;

  if (site >= 32) {   // bwd: row slices, coalesced both sides
    _Float16* ob = mtb + (size_t)(site - 32) * 65536 + p * 16384;
#pragma unroll
    for (int i = 0; i < 2; ++i) {
      const int w = i * 4 + wave;
      const float4* rp =
          (const float4*)(sb + (w * 16 + me) * 128 + (kh * 4 + q4) * 8);
      float4 f0 = rp[0], f1 = rp[1];
      v8h v = {(_Float16)f0.x, (_Float16)f0.y, (_Float16)f0.z, (_Float16)f0.w,
               (_Float16)f1.x, (_Float16)f1.y, (_Float16)f1.z, (_Float16)f1.w};
      *(v8h*)(ob + kh * 4096 + w * 512 + q4 * 128 + me * 8) = v;
    }
    return;
  }
  // fwd: column gather (register transpose)
  _Float16* ob = mtf + (size_t)site * 65536 + p * 16384;
#pragma unroll
  for (int i = 0; i < 2; ++i) {
    const int w = i * 4 + wave;
    v8h v;
#pragma unroll
    for (int j = 0; j < 8; ++j)
      v[j] = (_Float16)sb[((kh * 4 + q4) * 8 + j) * 128 + w * 16 + me];
    *(v8h*)(ob + kh * 4096 + w * 512 + q4 * 128 + me * 8) = v;
  }
}

// ---------------------------------------------------------------------------
// Half-chain kernel, R11: register-resident B-frags, depth-2 prefetch.
//   256 WGs x 8 waves x 16 elements; even blockIdx = fwd (u = l^T prod M),
//   odd = bwd (w = prod M r) — R2/R9 mapping (R10's XCD segregation was
//   neutral, reverted).
//   R9/R10 had depth-1 prefetch: site s's 16 loads issued exactly one
//   site-time before the vmcnt gate — zero slack, so L2/barrier jitter
//   landed on the critical path.  R11 rotates THREE register banks
//   (A,B,C; static rotation, no runtime indexing -> no scratch): at the
//   consume of site s, loads for s+1 AND s+2 are in flight (32
//   outstanding), giving each chunk two site-times of slack.
//   plds read for s+1 is hoisted ahead of the fence (removes ~120 cyc of
//   post-barrier LDS latency from the serial path).
// Frag layouts: A[m=lane&15][k=q4*8+j], B^T[n=me][k], C[row=q4*4+r][col=me].
// v LDS layout (R7-proven): v[e*128 + (seg^(e&7))*8 + j].
// ---------------------------------------------------------------------------
__global__ __launch_bounds__(512, 2) void mps_half_chain(
    const int* __restrict__ onstate, const _Float16* __restrict__ mtf,
    const _Float16* __restrict__ mtb, const float* __restrict__ left_vec,
    const float* __restrict__ right_vec, float* __restrict__ ut,
    float* __restrict__ wt) {
  __shared__ _Float16 vlds[2][2048];   // 2 x 4 KB v ping-pong
  __shared__ int plds[L * EPW];        // 4 KB occupations
  const int tid = threadIdx.x;
  const int wave = tid >> 6, lane = tid & 63;
  const int me = lane & 15, q4 = lane >> 4;
  const bool fwd = !(blockIdx.x & 1);
  const int b0 = (blockIdx.x >> 1) * EPW;
  const _Float16* mbase = fwd ? mtf : mtb;
  const float* ivec = fwd ? left_vec : right_vec;
  float* ovec = fwd ? ut : wt;

  // ---- stage onstate -> plds[site][e] (global site index)
#pragma unroll
  for (int j = 0; j < 2; ++j) {
    int idx = tid + j * 512;
    int e = idx >> 6, i = idx & 63;
    plds[i * EPW + e] = onstate[(b0 + e) * L + i];
  }
  // ---- init v = ivec for every element (swizzled fp16)
  if (tid < 256) {
    int e = tid >> 4, seg = tid & 15;
    _Float16* vp = &vlds[0][0] + e * 128 + (seg ^ (e & 7)) * 8;
#pragma unroll
    for (int j = 0; j < 8; ++j) vp[j] = (_Float16)ivec[seg * 8 + j];
  }

  // per-lane site-invariant global base for my 16 frags
  const _Float16* gbase = mbase + wave * 512 + lane * 8;
  auto stageR = [&](v8h (&bank)[16], int ls) {
    const v8h* gp = (const v8h*)(gbase + (size_t)ls * 65536);
#pragma unroll
    for (int i = 0; i < 16; ++i) bank[i] = gp[i * 512];  // stride 8 KB
  };
  // consume both k-halves of a bank into acc (masked by pm)
  auto consumeSite = [&](v8h (&bank)[16], int pm, const _Float16* vb,
                         v4f& acc) {
#pragma unroll
    for (int h = 0; h < 2; ++h) {
      const int s0 = h * 8 + q4, s1 = s0 + 4;
      v8h a0 = *(const v8h*)(vb + me * 128 + (s0 ^ (me & 7)) * 8);
      v8h a1 = *(const v8h*)(vb + me * 128 + (s1 ^ (me & 7)) * 8);
#pragma unroll
      for (int p = 0; p < P; ++p) {
        const bool isp = (pm == p);
        v8h zf = {};
        v8h am0 = isp ? a0 : zf;
        v8h am1 = isp ? a1 : zf;
        acc = __builtin_amdgcn_mfma_f32_16x16x32_f16(am0, bank[p * 4 + 2 * h],
                                                     acc, 0, 0, 0);
        acc = __builtin_amdgcn_mfma_f32_16x16x32_f16(
            am1, bank[p * 4 + 2 * h + 1], acc, 0, 0, 0);
      }
    }
  };
  const int c0 = wave * 16 + me;      // my output column
  auto writeV = [&](_Float16* vn, const v4f& acc) {
#pragma unroll
    for (int r = 0; r < 4; ++r) {
      int e = q4 * 4 + r;
      vn[e * 128 + ((c0 >> 3) ^ (e & 7)) * 8 + (c0 & 7)] = (_Float16)acc[r];
    }
  };
  auto lsOf = [&](int s) { return fwd ? s : 31 - s; };
  auto sgOf = [&](int s) { return fwd ? s : 63 - s; };

  __syncthreads();                    // plds + v-init visible (full drain, 1x)

  v8h bankA[16], bankB[16], bankC[16];
  stageR(bankA, lsOf(0));             // prologue: sites 0,1 in flight
  stageR(bankB, lsOf(1));

  int pm = plds[sgOf(0) * EPW + me];
  v4f accL = {0.f, 0.f, 0.f, 0.f};

  // one site step; cur = bank holding site s, nx2 = bank to receive s+2.
  // doStage/notLast are call-site literals -> fully folded.
  auto siteStep = [&](int s, v8h (&cur)[16], v8h (&nx2)[16], bool doStage,
                      bool notLast) {
    if (doStage) stageR(nx2, lsOf(s + 2));
    v4f acc = {0.f, 0.f, 0.f, 0.f};
    consumeSite(cur, pm, &vlds[s & 1][0], acc);
    if (notLast) {
      pm = plds[sgOf(s + 1) * EPW + me];   // hoisted next-site occupation
      writeV(&vlds[(s + 1) & 1][0], acc);
      // publish v-exchange; prefetched loads stay in flight across barrier
      __builtin_amdgcn_sched_barrier(0);
      __builtin_amdgcn_s_waitcnt(WAIT_LGKM0);
      __builtin_amdgcn_s_barrier();
      __builtin_amdgcn_sched_barrier(0);
    } else {
      accL = acc;
    }
  };

  // bank rotation: site s lives in bank s%3; s+2 goes into bank (s+2)%3.
  for (int g = 0; g < 10; ++g) {      // sites 0..29, rolled (I$-friendly)
    const int s = 3 * g;
    siteStep(s,     bankA, bankC, true, true);
    siteStep(s + 1, bankB, bankA, true, true);
    siteStep(s + 2, bankC, bankB, true, true);
  }
  siteStep(30, bankA, bankC, false, true);    // no more staging
  siteStep(31, bankB, bankA, false, false);

  // ---- epilogue: store half-chain vector transposed [d][b] (fp32)
#pragma unroll
  for (int r = 0; r < 4; ++r) ovec[c0 * B + b0 + q4 * 4 + r] = accL[r];
}

// ---------------------------------------------------------------------------
// Combine: amp[b] = sum_d u[d][b] * w[d][b]  (coalesced along b)
// 32 blocks — 4 waves split d-range, LDS cross-wave reduce.
// ---------------------------------------------------------------------------
__global__ void combine_uw(const float* __restrict__ ut,
                           const float* __restrict__ wt,
                           float* __restrict__ out) {
  __shared__ float red[256];
  const int t = threadIdx.x;
  const int b = blockIdx.x * 64 + (t & 63);
  const int w = t >> 6;
  float s = 0.f;
#pragma unroll
  for (int i = 0; i < 32; ++i) {
    const int d = w * 32 + i;
    s += ut[d * B + b] * wt[d * B + b];
  }
  red[t] = s;
  __syncthreads();
  if (t < 64) out[b] = red[t] + red[t + 64] + red[t + 128] + red[t + 192];
}

// ---------------------------------------------------------------------------
extern "C" void kernel_launch(void* const* d_in, const int* in_sizes, int n_in,
                              void* d_out, int out_size, void* d_ws,
                              size_t ws_size, hipStream_t stream) {
  const int*   onstate      = (const int*)d_in[0];
  const float* site_tensors = (const float*)d_in[1];
  const float* left_vec     = (const float*)d_in[2];
  const float* right_vec    = (const float*)d_in[3];
  float*       out          = (float*)d_out;
  char*        ws           = (char*)d_ws;   // needs 10 MB
  float*       ut           = (float*)(ws + UT_OFF);
  float*       wt           = (float*)(ws + WT_OFF);
  _Float16*    mtf          = (_Float16*)(ws + MTF_OFF);
  _Float16*    mtb          = (_Float16*)(ws + MTB_OFF);

  convert_dual<<<L * P * 4, 256, 0, stream>>>(site_tensors, mtf, mtb);
  mps_half_chain<<<2 * NG, 512, 0, stream>>>(
      onstate, mtf, mtb, left_vec, right_vec, ut, wt);
  combine_uw<<<B / 64, 256, 0, stream>>>(ut, wt, out);
}

// Round 5
// 115.283 us; speedup vs baseline: 1.0566x; 1.0566x over previous
//
#include <hip/hip_runtime.h>
#include <hip/hip_fp16.h>

// Problem constants (fixed by the reference)
constexpr int L = 64;     // sites
constexpr int P = 4;      // physical dim
constexpr int D = 128;    // bond dim
constexpr int B = 2048;   // batch
constexpr int EPW = 16;   // batch elements per WG (one mfma M-tile)
constexpr int NG = B / EPW;   // 128 batch groups -> 256 WGs (fwd+bwd)

using v8h = __attribute__((ext_vector_type(8))) _Float16;  // mfma A/B frag
using v4f = __attribute__((ext_vector_type(4))) float;     // mfma C/D frag

// ---- workspace layout (bytes); TOTAL 10 MB ------------------------------
constexpr size_t UT_OFF  = 0;               // u_t fp32 [d][b]   1 MB
constexpr size_t WT_OFF  = 1048576;         // w_t fp32 [d][b]   1 MB
constexpr size_t MTF_OFF = 2097152;         // sites 0..31  fp16 frag-layout 4 MB
constexpr size_t MTB_OFF = 6291456;         // sites 32..63 fp16 frag-layout 4 MB
// frag layout (fp16 units): [site][p][kh][w][q4][me][j]
//   site stride 65536, p 16384, kh 4096, w 512, q4 128, me 8, j 1
// frag (p,kh) for lane (w,q4,me) = B^T[col=w*16+me][k=(kh*4+q4)*8 + j]
// -> one global_load_dwordx4 per frag, 64 lanes = 1 KB contiguous.

// s_waitcnt immediates (gfx9: vmcnt[3:0] | exp<<4 | lgkm<<8 | vmcnt[5:4]<<14)
#define WAIT_LGKM0 0xC07F  // lgkmcnt(0) only; vmcnt untouched

// ---------------------------------------------------------------------------
// Convert fp32 src[site][p][d][c] (row-major 128x128) into frag layout.
//   fwd (sites 0..31):  B^T[col][k] = M[k][col]  -> column gather (register
//     transpose, 64B-coalesced across me-lanes)
//   bwd (sites 32..63): B^T[col][k] = M[col][k]  -> row slice, fully
//     coalesced float4 reads AND v8h writes.
// grid 512 x 256: block = (mat, kh-half); 4 waves x 4 (kh,w) combos.
// (R2-proven version, reverted from R4's quartering.)
// ---------------------------------------------------------------------------
__global__ void convert_dual(const float* __restrict__ src,
                             _Float16* __restrict__ mtf,
                             _Float16* __restrict__ mtb) {
  const int mat  = blockIdx.x >> 1;   // site*P + p
  const int half = blockIdx.x & 1;
  const int site = mat >> 2, p = mat & 3;
  const int wave = threadIdx.x >> 6, lane = threadIdx.x & 63;
  const int me = lane & 15, q4 = lane >> 4;
  const float* sb = src + (size_t)mat * 16384;

  if (site >= 32) {   // bwd: row slices, coalesced both sides
    _Float16* ob = mtb + (size_t)(site - 32) * 65536 + p * 16384;
#pragma unroll
    for (int i = 0; i < 4; ++i) {
      const int kh = half * 2 + (i >> 1);
      const int w  = (i & 1) * 4 + wave;
      const float4* rp =
          (const float4*)(sb + (w * 16 + me) * 128 + (kh * 4 + q4) * 8);
      float4 f0 = rp[0], f1 = rp[1];
      v8h v = {(_Float16)f0.x, (_Float16)f0.y, (_Float16)f0.z, (_Float16)f0.w,
               (_Float16)f1.x, (_Float16)f1.y, (_Float16)f1.z, (_Float16)f1.w};
      *(v8h*)(ob + kh * 4096 + w * 512 + q4 * 128 + me * 8) = v;
    }
    return;
  }
  // fwd: column gather (register transpose)
  _Float16* ob = mtf + (size_t)site * 65536 + p * 16384;
#pragma unroll
  for (int i = 0; i < 4; ++i) {
    const int kh = half * 2 + (i >> 1);
    const int w  = (i & 1) * 4 + wave;
    v8h v;
#pragma unroll
    for (int j = 0; j < 8; ++j)
      v[j] = (_Float16)sb[((kh * 4 + q4) * 8 + j) * 128 + w * 16 + me];
    *(v8h*)(ob + kh * 4096 + w * 512 + q4 * 128 + me * 8) = v;
  }
}

// ---------------------------------------------------------------------------
// Half-chain kernel, R12 = R9 (best measured, 115.9 total) + 4-way
// accumulator split.
//   256 WGs x 8 waves x 16 elements; even blockIdx = fwd, odd = bwd.
//   Per site per wave: 16 global_load_dwordx4 into a v8h bank (frag
//   layout above), 16 masked MFMAs, v exchanged through a 4 KB LDS
//   ping-pong; banks double-buffered in registers (depth-1 — R11's
//   depth-2 collapsed: allocator refused 3 live banks, VGPR=120).
//   R12 change: the 16 MFMAs previously formed ONE dependent chain on a
//   single acc (~320 cyc latency on the serial per-site path).  Now 4
//   independent chains of 4 (h-half x p-pair) + 3 vector adds; all 4
//   A-frag ds_reads hoisted.  Serial latency ~100 cyc; VGPR +28.
// Frag layouts: A[m=lane&15][k=q4*8+j], B^T[n=me][k], C[row=q4*4+r][col=me].
// v LDS layout (R7-proven): v[e*128 + (seg^(e&7))*8 + j].
// ---------------------------------------------------------------------------
__global__ __launch_bounds__(512, 2) void mps_half_chain(
    const int* __restrict__ onstate, const _Float16* __restrict__ mtf,
    const _Float16* __restrict__ mtb, const float* __restrict__ left_vec,
    const float* __restrict__ right_vec, float* __restrict__ ut,
    float* __restrict__ wt) {
  __shared__ _Float16 vlds[2][2048];   // 2 x 4 KB v ping-pong
  __shared__ int plds[L * EPW];        // 4 KB occupations
  const int tid = threadIdx.x;
  const int wave = tid >> 6, lane = tid & 63;
  const int me = lane & 15, q4 = lane >> 4;
  const bool fwd = !(blockIdx.x & 1);
  const int b0 = (blockIdx.x >> 1) * EPW;
  const _Float16* mbase = fwd ? mtf : mtb;
  const float* ivec = fwd ? left_vec : right_vec;
  float* ovec = fwd ? ut : wt;

  // ---- stage onstate -> plds[site][e] (global site index)
#pragma unroll
  for (int j = 0; j < 2; ++j) {
    int idx = tid + j * 512;
    int e = idx >> 6, i = idx & 63;
    plds[i * EPW + e] = onstate[(b0 + e) * L + i];
  }
  // ---- init v = ivec for every element (swizzled fp16)
  if (tid < 256) {
    int e = tid >> 4, seg = tid & 15;
    _Float16* vp = &vlds[0][0] + e * 128 + (seg ^ (e & 7)) * 8;
#pragma unroll
    for (int j = 0; j < 8; ++j) vp[j] = (_Float16)ivec[seg * 8 + j];
  }

  // per-lane site-invariant global base for my 16 frags
  const _Float16* gbase = mbase + wave * 512 + lane * 8;
  auto stageR = [&](v8h (&bank)[16], int ls) {
    const v8h* gp = (const v8h*)(gbase + (size_t)ls * 65536);
#pragma unroll
    for (int i = 0; i < 16; ++i) bank[i] = gp[i * 512];  // stride 8 KB
  };
  // consume both k-halves of a bank into acc (masked by pm).
  // 4 independent MFMA chains of 4 (c00: h=0 p<2, c01: h=0 p>=2,
  // c10: h=1 p<2, c11: h=1 p>=2), summed at the end.
  auto consumeSite = [&](v8h (&bank)[16], int pm, const _Float16* vb,
                         v4f& acc) {
    // all 4 A-frags up front (independent ds_read_b128)
    v8h a0 = *(const v8h*)(vb + me * 128 + ((q4) ^ (me & 7)) * 8);
    v8h a1 = *(const v8h*)(vb + me * 128 + ((q4 + 4) ^ (me & 7)) * 8);
    v8h a2 = *(const v8h*)(vb + me * 128 + ((q4 + 8) ^ (me & 7)) * 8);
    v8h a3 = *(const v8h*)(vb + me * 128 + ((q4 + 12) ^ (me & 7)) * 8);
    v4f c00 = {0.f, 0.f, 0.f, 0.f}, c01 = {0.f, 0.f, 0.f, 0.f};
    v4f c10 = {0.f, 0.f, 0.f, 0.f}, c11 = {0.f, 0.f, 0.f, 0.f};
#pragma unroll
    for (int p = 0; p < P; ++p) {      // p compile-time under unroll
      const bool isp = (pm == p);
      v8h zf = {};
      v8h m0 = isp ? a0 : zf;
      v8h m1 = isp ? a1 : zf;
      v8h m2 = isp ? a2 : zf;
      v8h m3 = isp ? a3 : zf;
      v4f& cA = (p < 2) ? c00 : c01;
      v4f& cB = (p < 2) ? c10 : c11;
      cA = __builtin_amdgcn_mfma_f32_16x16x32_f16(m0, bank[p * 4 + 0], cA,
                                                  0, 0, 0);
      cA = __builtin_amdgcn_mfma_f32_16x16x32_f16(m1, bank[p * 4 + 1], cA,
                                                  0, 0, 0);
      cB = __builtin_amdgcn_mfma_f32_16x16x32_f16(m2, bank[p * 4 + 2], cB,
                                                  0, 0, 0);
      cB = __builtin_amdgcn_mfma_f32_16x16x32_f16(m3, bank[p * 4 + 3], cB,
                                                  0, 0, 0);
    }
    acc = acc + ((c00 + c01) + (c10 + c11));
  };
  const int c0 = wave * 16 + me;      // my output column
  auto writeV = [&](_Float16* vn, const v4f& acc) {
#pragma unroll
    for (int r = 0; r < 4; ++r) {
      int e = q4 * 4 + r;
      vn[e * 128 + ((c0 >> 3) ^ (e & 7)) * 8 + (c0 & 7)] = (_Float16)acc[r];
    }
  };

  __syncthreads();                    // plds + v-init visible (full drain, 1x)

  v8h bank0[16], bank1[16];
  stageR(bank0, fwd ? 0 : 31);        // prologue: site 0 frags in flight

  v4f accL = {0.f, 0.f, 0.f, 0.f};
  for (int s2 = 0; s2 < 16; ++s2) {
    const int se = 2 * s2, so = se + 1;
    // ---- even site: consume bank0, prefetch odd site -> bank1
    {
      const int sg = fwd ? se : 63 - se;
      const int pm = plds[sg * EPW + me];
      stageR(bank1, fwd ? so : 31 - so);
      v4f acc = {0.f, 0.f, 0.f, 0.f};
      consumeSite(bank0, pm, &vlds[0][0], acc);
      writeV(&vlds[1][0], acc);
      // publish v-exchange; bank1's 16 loads stay in flight across barrier
      __builtin_amdgcn_sched_barrier(0);
      __builtin_amdgcn_s_waitcnt(WAIT_LGKM0);
      __builtin_amdgcn_s_barrier();
      __builtin_amdgcn_sched_barrier(0);
    }
    // ---- odd site: consume bank1, prefetch next even site -> bank0
    {
      const int sg = fwd ? so : 63 - so;
      const int pm = plds[sg * EPW + me];
      const int sn = (so + 1) & 31;              // wrap at 31: harmless refetch
      stageR(bank0, fwd ? sn : 31 - sn);
      v4f acc = {0.f, 0.f, 0.f, 0.f};
      consumeSite(bank1, pm, &vlds[1][0], acc);
      if (so < 31) {
        writeV(&vlds[0][0], acc);
        __builtin_amdgcn_sched_barrier(0);
        __builtin_amdgcn_s_waitcnt(WAIT_LGKM0);
        __builtin_amdgcn_s_barrier();
        __builtin_amdgcn_sched_barrier(0);
      } else {
        accL = acc;
      }
    }
  }
  // ---- epilogue: store half-chain vector transposed [d][b] (fp32)
#pragma unroll
  for (int r = 0; r < 4; ++r) ovec[c0 * B + b0 + q4 * 4 + r] = accL[r];
}

// ---------------------------------------------------------------------------
// Combine: amp[b] = sum_d u[d][b] * w[d][b]  (coalesced along b)
// 32 blocks — 4 waves split d-range, LDS cross-wave reduce.
// ---------------------------------------------------------------------------
__global__ void combine_uw(const float* __restrict__ ut,
                           const float* __restrict__ wt,
                           float* __restrict__ out) {
  __shared__ float red[256];
  const int t = threadIdx.x;
  const int b = blockIdx.x * 64 + (t & 63);
  const int w = t >> 6;
  float s = 0.f;
#pragma unroll
  for (int i = 0; i < 32; ++i) {
    const int d = w * 32 + i;
    s += ut[d * B + b] * wt[d * B + b];
  }
  red[t] = s;
  __syncthreads();
  if (t < 64) out[b] = red[t] + red[t + 64] + red[t + 128] + red[t + 192];
}

// ---------------------------------------------------------------------------
extern "C" void kernel_launch(void* const* d_in, const int* in_sizes, int n_in,
                              void* d_out, int out_size, void* d_ws,
                              size_t ws_size, hipStream_t stream) {
  const int*   onstate      = (const int*)d_in[0];
  const float* site_tensors = (const float*)d_in[1];
  const float* left_vec     = (const float*)d_in[2];
  const float* right_vec    = (const float*)d_in[3];
  float*       out          = (float*)d_out;
  char*        ws           = (char*)d_ws;   // needs 10 MB
  float*       ut           = (float*)(ws + UT_OFF);
  float*       wt           = (float*)(ws + WT_OFF);
  _Float16*    mtf          = (_Float16*)(ws + MTF_OFF);
  _Float16*    mtb          = (_Float16*)(ws + MTB_OFF);

  convert_dual<<<L * P * 2, 256, 0, stream>>>(site_tensors, mtf, mtb);
  mps_half_chain<<<2 * NG, 512, 0, stream>>>(
      onstate, mtf, mtb, left_vec, right_vec, ut, wt);
  combine_uw<<<B / 64, 256, 0, stream>>>(ut, wt, out);
}